// Round 7
// baseline (68.559 us; speedup 1.0000x reference)
//
#include <hip/hip_runtime.h>
#include <stdint.h>

#define CLASS_NUM 7
#define QROWS 1050
#define QPAD  1152            // 18 tiles * 64 rows; pad rows are zero
#define NPAD  102             // each pad row adds exp2(0)=1 to dn
#define NTILES 18
#define TB    8192            // fp8 tile bytes: 64 rows x 128 cols
#define QSUM_OFF (QPAD * 128) // 147456: 7x128 fp32 class sums after fp8 queue
#define C2L 2.8853900817779268f   // 2/ln2 : exp(2s) = exp2(s*C2L)

typedef float f32x4 __attribute__((ext_vector_type(4)));
typedef long  long2v __attribute__((ext_vector_type(2)));

// pack 4 floats -> 4 fp8 e4m3 (OCP, RNE) in one dword
__device__ __forceinline__ unsigned pk8(float a, float b, float c, float d) {
  int v = __builtin_amdgcn_cvt_pk_fp8_f32(a, b, 0, false);
  v = __builtin_amdgcn_cvt_pk_fp8_f32(c, d, v, true);
  return (unsigned)v;
}

// ---- prep A: queue fp32 -> fp8, FRAGMENT-MAJOR tile image, zero-padded.
// 8-byte piece i: tile t = i>>10; j = i&1023; n=j>>8; k2=(j>>7)&1; lane=(j>>1)&63;
// kk=j&1 -> frag k = 2*k2+kk; piece = queue[t*64+n*16+(lane&15)][k*32+(lane>>4)*8 ..+8]
__global__ void prep_queue(const float* __restrict__ queue, unsigned* __restrict__ ws) {
  const int i = blockIdx.x * 256 + threadIdx.x;
  if (i >= QPAD * 16) return;
  const int t = i >> 10, j = i & 1023;
  const int n = j >> 8, k2 = (j >> 7) & 1, lane = (j >> 1) & 63, kk = j & 1;
  const int hi = lane >> 4, lo = lane & 15;
  const int row = t * 64 + n * 16 + lo;
  const int col = (k2 * 2 + kk) * 32 + hi * 8;
  unsigned d0 = 0, d1 = 0;
  if (row < QROWS) {
    const float4 v0 = *(const float4*)(queue + row * 128 + col);
    const float4 v1 = *(const float4*)(queue + row * 128 + col + 4);
    d0 = pk8(v0.x, v0.y, v0.z, v0.w);
    d1 = pk8(v1.x, v1.y, v1.z, v1.w);
  }
  ws[i * 2]     = d0;
  ws[i * 2 + 1] = d1;
}

// ---- prep B: per-class queue-row sums (fp32-exact positive-term path)
__global__ void prep_qsum(const float* __restrict__ queue, float* __restrict__ qsum) {
  const int c = blockIdx.x, d = threadIdx.x;      // 7 blocks x 128 threads
  float s = 0.f;
  const float* p = queue + c * 150 * 128 + d;
#pragma unroll 10
  for (int i = 0; i < 150; ++i) s += p[i * 128];
  qsum[c * 128 + d] = s;
}

// ---- fused main: 1024 blocks x 128 thr (2 waves), 64 B-rows/block, 32/wave.
__global__ __launch_bounds__(128, 4) void pgc_fused(
    const float* __restrict__ act, const float* __restrict__ ema,
    const float* __restrict__ plab, const char* __restrict__ ws,
    float* __restrict__ out)
{
  __shared__ __align__(16) char qT[2][TB];   // 16 KB: dbuf; qT[1] = A-bounce first

  const int tid = threadIdx.x, lane = tid & 63, wave = tid >> 6;
  const int lo = lane & 15, hi = lane >> 4;

  // issue tile-0 DMA immediately (hides under the prologue); A uses qT[1]
  {
    const char* gs = ws + wave * 4096 + lane * 16;
    char* ld = qT[0] + wave * 4096;
#pragma unroll
    for (int ii = 0; ii < 4; ++ii)
      __builtin_amdgcn_global_load_lds(
          (const __attribute__((address_space(1))) void*)(gs + ii * 1024),
          (__attribute__((address_space(3))) void*)(ld + ii * 1024), 16, 0, 0);
  }

  // ---- prologue: 2 threads/row; norms, lpos, label, pos-dot, A->fp8 frag-major
  float mylpos, mypd;
  {
    const int r = tid >> 1, h = tid & 1;
    const long grow = (long)blockIdx.x * 64 + r;
    const float* ap = act + grow * 128 + h * 64;
    const float* ep = ema + grow * 128 + h * 64;
    f32x4 a4[16];
    float a2 = 0.f, e2 = 0.f, ae = 0.f;
#pragma unroll
    for (int j = 0; j < 16; ++j) {
      a4[j] = *(const f32x4*)(ap + 4 * j);
      const float4 ev = *(const float4*)(ep + 4 * j);
      a2 += a4[j].x*a4[j].x + a4[j].y*a4[j].y + a4[j].z*a4[j].z + a4[j].w*a4[j].w;
      e2 += ev.x*ev.x + ev.y*ev.y + ev.z*ev.z + ev.w*ev.w;
      ae += a4[j].x*ev.x + a4[j].y*ev.y + a4[j].z*ev.z + a4[j].w*ev.w;
    }
    a2 += __shfl_xor(a2, 1); e2 += __shfl_xor(e2, 1); ae += __shfl_xor(ae, 1);
    const float rna = rsqrtf(a2), rne = rsqrtf(e2);
    mylpos = ae * rna * rne * C2L;

    int mylab;
    {
      const float* pp = plab + grow * CLASS_NUM;
      float best = pp[0]; int bi = 0;
#pragma unroll
      for (int c = 1; c < CLASS_NUM; ++c) {
        const float v = pp[c];
        if (v > best) { best = v; bi = c; }
      }
      mylab = bi;
    }
    {
      const float* qs = (const float*)(ws + QSUM_OFF) + mylab * 128 + h * 64;
      float pdot = 0.f;
#pragma unroll
      for (int j = 0; j < 16; ++j) {
        const float4 qv = *(const float4*)(qs + 4 * j);
        pdot += a4[j].x*qv.x + a4[j].y*qv.y + a4[j].z*qv.z + a4[j].w*qv.w;
      }
      pdot *= rna;
      mypd = pdot + __shfl_xor(pdot, 1);
    }

    // stage A into qT[1], frag-major: addr = w*4096 + (s*4+k)*512 + (h2*16+lr)*8
    const float sc = rna * C2L;   // pre-scale so MFMA output is 2s/ln2
    const int w = r >> 5, s = (r >> 4) & 1, lr = r & 15;
#pragma unroll
    for (int kk = 0; kk < 2; ++kk) {
      const int k = h * 2 + kk;
#pragma unroll
      for (int h2 = 0; h2 < 4; ++h2) {
        const f32x4 x = a4[kk * 8 + h2 * 2], y = a4[kk * 8 + h2 * 2 + 1];
        uint2 u;
        u.x = pk8(x.x * sc, x.y * sc, x.z * sc, x.w * sc);
        u.y = pk8(y.x * sc, y.y * sc, y.z * sc, y.w * sc);
        *(uint2*)(qT[1] + w * 4096 + (s * 4 + k) * 512 + (h2 * 16 + lr) * 8) = u;
      }
    }
  }
  __syncthreads();   // A staged + tile-0 DMA drained

  // per-wave A fragments (2 sets of 16 rows), contiguous lane*8 reads
  long af[2][4];
#pragma unroll
  for (int s = 0; s < 2; ++s)
#pragma unroll
    for (int k = 0; k < 4; ++k)
      af[s][k] = *(const long*)(qT[1] + wave * 4096 + (s * 4 + k) * 512 + lane * 8);
  __syncthreads();   // all afrag reads done before tile-1 DMA reuses qT[1]

  float dn[2][4] = {{0.f,0.f,0.f,0.f},{0.f,0.f,0.f,0.f}};
  const char* qb = qT[0] + lane * 16;                    // imm-offset reads
  const char* gp = ws + TB + wave * 4096 + lane * 16;    // next-tile DMA src

#define TILE_BODY(BUF, PF)                                                     \
  {                                                                            \
    if (PF) {                                                                  \
      char* ld = qT[(BUF) ^ 1] + wave * 4096;                                  \
      _Pragma("unroll")                                                        \
      for (int ii = 0; ii < 4; ++ii)                                           \
        __builtin_amdgcn_global_load_lds(                                      \
            (const __attribute__((address_space(1))) void*)(gp + ii * 1024),   \
            (__attribute__((address_space(3))) void*)(ld + ii * 1024), 16,0,0);\
      gp += TB;                                                                \
    }                                                                          \
    _Pragma("unroll")                                                          \
    for (int n = 0; n < 4; ++n) {                                              \
      const long2v g0 = *(const long2v*)(qb + (BUF) * TB + n * 2048);          \
      const long2v g1 = *(const long2v*)(qb + (BUF) * TB + n * 2048 + 1024);   \
      f32x4 a0 = {0.f,0.f,0.f,0.f}, a1 = {0.f,0.f,0.f,0.f};                    \
      a0 = __builtin_amdgcn_mfma_f32_16x16x32_fp8_fp8(af[0][0], g0.x, a0,0,0,0);\
      a1 = __builtin_amdgcn_mfma_f32_16x16x32_fp8_fp8(af[1][0], g0.x, a1,0,0,0);\
      a0 = __builtin_amdgcn_mfma_f32_16x16x32_fp8_fp8(af[0][1], g0.y, a0,0,0,0);\
      a1 = __builtin_amdgcn_mfma_f32_16x16x32_fp8_fp8(af[1][1], g0.y, a1,0,0,0);\
      a0 = __builtin_amdgcn_mfma_f32_16x16x32_fp8_fp8(af[0][2], g1.x, a0,0,0,0);\
      a1 = __builtin_amdgcn_mfma_f32_16x16x32_fp8_fp8(af[1][2], g1.x, a1,0,0,0);\
      a0 = __builtin_amdgcn_mfma_f32_16x16x32_fp8_fp8(af[0][3], g1.y, a0,0,0,0);\
      a1 = __builtin_amdgcn_mfma_f32_16x16x32_fp8_fp8(af[1][3], g1.y, a1,0,0,0);\
      _Pragma("unroll")                                                        \
      for (int rg = 0; rg < 4; ++rg) {                                         \
        dn[0][rg] += exp2f(a0[rg]);                                            \
        dn[1][rg] += exp2f(a1[rg]);                                            \
      }                                                                        \
    }                                                                          \
    __syncthreads();                                                           \
  }

#pragma unroll 1
  for (int p = 0; p < 9; ++p) {
    TILE_BODY(0, true)        // tile 2p   (prefetch 2p+1 -> qT[1])
    TILE_BODY(1, (p < 8))     // tile 2p+1 (prefetch 2p+2 -> qT[0])
  }
#undef TILE_BODY

  // reduce across the 16 q-column lanes of each row
#pragma unroll
  for (int s = 0; s < 2; ++s)
#pragma unroll
    for (int rg = 0; rg < 4; ++rg)
#pragma unroll
      for (int m = 1; m < 16; m <<= 1)
        dn[s][rg] += __shfl_xor(dn[s][rg], m);

  float loss = 0.f;
  if (lo == 0) {
#pragma unroll
    for (int s = 0; s < 2; ++s)
#pragma unroll
      for (int rg = 0; rg < 4; ++rg) {
        const int idx = (s * 16 + hi * 4 + rg) * 2;   // wave-lane holding row stats
        const float lp  = exp2f(__shfl(mylpos, idx)); // exp(2*<f,ema_f>)
        const float pdr = __shfl(mypd, idx);          // fp32 positive dot sum
        const float dnf = lp + dn[s][rg] - (float)NPAD;
        loss += -logf(lp / dnf + 1e-8f) + 150.0f * logf(dnf) - 2.0f * pdr;
      }
  }
#pragma unroll
  for (int m = 1; m < 64; m <<= 1) loss += __shfl_xor(loss, m);

  float* swsum = (float*)qT[0];   // qT dead after the sweep's final barrier
  if (lane == 0) swsum[wave] = loss;
  __syncthreads();
  if (tid == 0)
    atomicAdd(out, (swsum[0] + swsum[1]) * (1.0f / (151.0f * 65536.0f)));
}

extern "C" void kernel_launch(void* const* d_in, const int* in_sizes, int n_in,
                              void* d_out, int out_size, void* d_ws, size_t ws_size,
                              hipStream_t stream) {
  const float* act   = (const float*)d_in[0];
  const float* ema   = (const float*)d_in[1];
  const float* plab  = (const float*)d_in[2];
  const float* queue = (const float*)d_in[3];
  float* out = (float*)d_out;

  hipMemsetAsync(d_out, 0, sizeof(float), stream);

  prep_queue<<<dim3((QPAD * 16 + 255) / 256), dim3(256), 0, stream>>>(
      queue, (unsigned*)d_ws);
  prep_qsum<<<dim3(CLASS_NUM), dim3(128), 0, stream>>>(
      queue, (float*)((char*)d_ws + QSUM_OFF));

  pgc_fused<<<dim3(1024), dim3(128), 0, stream>>>(
      act, ema, plab, (const char*)d_ws, out);
}

// Round 8
// 62.867 us; speedup vs baseline: 1.0905x; 1.0905x over previous
//
#include <hip/hip_runtime.h>
#include <stdint.h>

#define CLASS_NUM 7
#define QROWS 1050
#define QPAD  1152              // 72 groups * 16 rows; pad rows are zero
#define NPAD  102               // pad rows each add exp2(0)=1 to denom
#define NGRP  72
#define QSUM_OFF (QPAD * 128)   // 147456: 7x128 fp32 class sums (after fp8 image)
#define C2L 2.8853900817779268f // 2/ln2 : exp(2s) = exp2(s*C2L)

typedef float f32x4 __attribute__((ext_vector_type(4)));
typedef long  long2v __attribute__((ext_vector_type(2)));

// pack 4 floats -> 4 fp8 e4m3 (OCP, RNE) in one dword
__device__ __forceinline__ unsigned pk8(float a, float b, float c, float d) {
  int v = __builtin_amdgcn_cvt_pk_fp8_f32(a, b, 0, false);
  v = __builtin_amdgcn_cvt_pk_fp8_f32(c, d, v, true);
  return (unsigned)v;
}

// ---- prep: (a) queue fp32 -> fp8 fragment-major image [g][lane][k] (8B piece
// at g*2048 + lane*32 + k*8 holds queue[g*16+(lane&15)][k*32+(lane>>4)*8 ..+8]);
// (b) per-class column sums via run-based atomics (qsum zeroed by memset).
__global__ __launch_bounds__(256) void prep_q8(
    const float* __restrict__ queue, char* __restrict__ ws)
{
  const int g = blockIdx.x, tid = threadIdx.x;
  // (a) fp8 conversion: piece p = g*256 + tid
  {
    const int lane = tid >> 2, k = tid & 3;
    const int row = g * 16 + (lane & 15);
    const int col = k * 32 + (lane >> 4) * 8;
    uint2 u = {0u, 0u};
    if (row < QROWS) {
      const float4 v0 = *(const float4*)(queue + row * 128 + col);
      const float4 v1 = *(const float4*)(queue + row * 128 + col + 4);
      u.x = pk8(v0.x, v0.y, v0.z, v0.w);
      u.y = pk8(v1.x, v1.y, v1.z, v1.w);
    }
    *(uint2*)(ws + (size_t)g * 2048 + tid * 8) = u;
  }
  // (b) class sums: col = tid&127, rows g*16 + (tid>>7)*8 .. +8
  {
    float* qsum = (float*)(ws + QSUM_OFF);
    const int col = tid & 127;
    const int rbase = g * 16 + (tid >> 7) * 8;
    int c0 = -1; float s = 0.f;
#pragma unroll
    for (int rr = 0; rr < 8; ++rr) {
      const int row = rbase + rr;
      if (row < QROWS) {
        const int c = (row * 6991) >> 20;          // row/150, exact for row<14169
        if (c != c0) {
          if (c0 >= 0) atomicAdd(&qsum[c0 * 128 + col], s);
          c0 = c; s = 0.f;
        }
        s += queue[row * 128 + col];
      }
    }
    if (c0 >= 0) atomicAdd(&qsum[c0 * 128 + col], s);
  }
}

// ---- main: 512 blocks x 256 thr (4 waves, 32 B-rows/wave). Barrier-free
// streaming sweep: B-frags straight from global (L1/L2-hot) into registers.
__global__ __launch_bounds__(256, 2) void pgc_stream(
    const float* __restrict__ act, const float* __restrict__ ema,
    const float* __restrict__ plab, const char* __restrict__ ws,
    float* __restrict__ out)
{
  __shared__ __align__(16) char aT[16384];   // A-frag exchange (16 KB), then swsum

  const int tid = threadIdx.x, lane = tid & 63, wave = tid >> 6;
  const int lo = lane & 15, hi = lane >> 4;

  // ---- prologue: 2 threads/row; norms, lpos, label, pos-dot, A->fp8 frag-major
  float mylpos, mypd;
  {
    const int r = tid >> 1, h = tid & 1;
    const long grow = (long)blockIdx.x * 128 + r;
    const float* ap = act + grow * 128 + h * 64;
    const float* ep = ema + grow * 128 + h * 64;
    f32x4 a4[16];
    float a2 = 0.f, e2 = 0.f, ae = 0.f;
#pragma unroll
    for (int j = 0; j < 16; ++j) {
      a4[j] = *(const f32x4*)(ap + 4 * j);
      const float4 ev = *(const float4*)(ep + 4 * j);
      a2 += a4[j].x*a4[j].x + a4[j].y*a4[j].y + a4[j].z*a4[j].z + a4[j].w*a4[j].w;
      e2 += ev.x*ev.x + ev.y*ev.y + ev.z*ev.z + ev.w*ev.w;
      ae += a4[j].x*ev.x + a4[j].y*ev.y + a4[j].z*ev.z + a4[j].w*ev.w;
    }
    a2 += __shfl_xor(a2, 1); e2 += __shfl_xor(e2, 1); ae += __shfl_xor(ae, 1);
    const float rna = rsqrtf(a2), rne = rsqrtf(e2);
    mylpos = ae * rna * rne * C2L;

    int mylab;
    {
      const float* pp = plab + grow * CLASS_NUM;
      float best = pp[0]; int bi = 0;
#pragma unroll
      for (int c = 1; c < CLASS_NUM; ++c) {
        const float v = pp[c];
        if (v > best) { best = v; bi = c; }
      }
      mylab = bi;
    }
    {
      const float* qs = (const float*)(ws + QSUM_OFF) + mylab * 128 + h * 64;
      float pdot = 0.f;
#pragma unroll
      for (int j = 0; j < 16; ++j) {
        const float4 qv = *(const float4*)(qs + 4 * j);
        pdot += a4[j].x*qv.x + a4[j].y*qv.y + a4[j].z*qv.z + a4[j].w*qv.w;
      }
      pdot *= rna;
      mypd = pdot + __shfl_xor(pdot, 1);
    }

    // stage A frag-major: [w][s][dlane][k] = w*4096 + s*2048 + dlane*32 + k*8
    const float sc = rna * C2L;   // pre-scale so MFMA output is 2s/ln2
    const int w = r >> 5, s = (r >> 4) & 1, lr = r & 15;
#pragma unroll
    for (int kk = 0; kk < 2; ++kk) {
      const int k = h * 2 + kk;
#pragma unroll
      for (int h2 = 0; h2 < 4; ++h2) {
        const f32x4 x = a4[kk * 8 + h2 * 2], y = a4[kk * 8 + h2 * 2 + 1];
        uint2 u;
        u.x = pk8(x.x * sc, x.y * sc, x.z * sc, x.w * sc);
        u.y = pk8(y.x * sc, y.y * sc, y.z * sc, y.w * sc);
        *(uint2*)(aT + w * 4096 + s * 2048 + (h2 * 16 + lr) * 32 + k * 8) = u;
      }
    }
  }
  __syncthreads();

  // per-wave A fragments: set0 (la0={k0,k1}, la1={k2,k3}), set1 (lb0, lb1)
  const long2v la0 = *(const long2v*)(aT + wave * 4096 + lane * 32);
  const long2v la1 = *(const long2v*)(aT + wave * 4096 + lane * 32 + 16);
  const long2v lb0 = *(const long2v*)(aT + wave * 4096 + 2048 + lane * 32);
  const long2v lb1 = *(const long2v*)(aT + wave * 4096 + 2048 + lane * 32 + 16);

  float dn0[4] = {0.f, 0.f, 0.f, 0.f};
  float dn1[4] = {0.f, 0.f, 0.f, 0.f};
  const f32x4 Z = {0.f, 0.f, 0.f, 0.f};
  const char* qp = ws + (size_t)lane * 32;

  long2v B0a, B0b, B1a, B1b, B2a, B2b;
#define LOADG(Xa, Xb, G)                                                \
  { Xa = *(const long2v*)(qp + (G) * 2048);                             \
    Xb = *(const long2v*)(qp + (G) * 2048 + 16); }
#define COMPG(Xa, Xb)                                                   \
  { f32x4 c0 = Z, c1 = Z;                                               \
    c0 = __builtin_amdgcn_mfma_f32_16x16x32_fp8_fp8(la0[0], Xa[0], c0, 0, 0, 0); \
    c1 = __builtin_amdgcn_mfma_f32_16x16x32_fp8_fp8(lb0[0], Xa[0], c1, 0, 0, 0); \
    c0 = __builtin_amdgcn_mfma_f32_16x16x32_fp8_fp8(la0[1], Xa[1], c0, 0, 0, 0); \
    c1 = __builtin_amdgcn_mfma_f32_16x16x32_fp8_fp8(lb0[1], Xa[1], c1, 0, 0, 0); \
    c0 = __builtin_amdgcn_mfma_f32_16x16x32_fp8_fp8(la1[0], Xb[0], c0, 0, 0, 0); \
    c1 = __builtin_amdgcn_mfma_f32_16x16x32_fp8_fp8(lb1[0], Xb[0], c1, 0, 0, 0); \
    c0 = __builtin_amdgcn_mfma_f32_16x16x32_fp8_fp8(la1[1], Xb[1], c0, 0, 0, 0); \
    c1 = __builtin_amdgcn_mfma_f32_16x16x32_fp8_fp8(lb1[1], Xb[1], c1, 0, 0, 0); \
    _Pragma("unroll")                                                   \
    for (int rg = 0; rg < 4; ++rg) {                                    \
      dn0[rg] += exp2f(c0[rg]);                                         \
      dn1[rg] += exp2f(c1[rg]);                                         \
    } }

  LOADG(B0a, B0b, 0)
  LOADG(B1a, B1b, 1)
#pragma unroll 1
  for (int g = 0; g < 69; g += 3) {
    LOADG(B2a, B2b, g + 2)
    COMPG(B0a, B0b)
    LOADG(B0a, B0b, g + 3)
    COMPG(B1a, B1b)
    LOADG(B1a, B1b, g + 4)
    COMPG(B2a, B2b)
  }
  // peel: groups 69,70,71 (B0=69, B1=70 already loaded)
  LOADG(B2a, B2b, 71)
  COMPG(B0a, B0b)
  COMPG(B1a, B1b)
  COMPG(B2a, B2b)
#undef LOADG
#undef COMPG

  // reduce across the 16 q-column lanes of each row
#pragma unroll
  for (int rg = 0; rg < 4; ++rg)
#pragma unroll
    for (int m = 1; m < 16; m <<= 1) {
      dn0[rg] += __shfl_xor(dn0[rg], m);
      dn1[rg] += __shfl_xor(dn1[rg], m);
    }

  float loss = 0.f;
  if (lo == 0) {
#pragma unroll
    for (int s = 0; s < 2; ++s)
#pragma unroll
      for (int rg = 0; rg < 4; ++rg) {
        const int idx = (s * 16 + hi * 4 + rg) * 2;   // wave-lane holding row stats
        const float lp  = exp2f(__shfl(mylpos, idx)); // exp(2*<f,ema_f>)
        const float pdr = __shfl(mypd, idx);          // fp32 positive dot sum
        const float dnf = lp + (s ? dn1[rg] : dn0[rg]) - (float)NPAD;
        loss += -logf(lp / dnf + 1e-8f) + 150.0f * logf(dnf) - 2.0f * pdr;
      }
  }
#pragma unroll
  for (int m = 1; m < 64; m <<= 1) loss += __shfl_xor(loss, m);

  __syncthreads();                 // all A-frag/LDS reads done; reuse aT
  float* swsum = (float*)aT;
  if (lane == 0) swsum[wave] = loss;
  __syncthreads();
  if (tid == 0)
    atomicAdd(out, (swsum[0] + swsum[1] + swsum[2] + swsum[3]) *
                       (1.0f / (151.0f * 65536.0f)));
}

extern "C" void kernel_launch(void* const* d_in, const int* in_sizes, int n_in,
                              void* d_out, int out_size, void* d_ws, size_t ws_size,
                              hipStream_t stream) {
  const float* act   = (const float*)d_in[0];
  const float* ema   = (const float*)d_in[1];
  const float* plab  = (const float*)d_in[2];
  const float* queue = (const float*)d_in[3];
  float* out = (float*)d_out;

  hipMemsetAsync(d_out, 0, sizeof(float), stream);
  hipMemsetAsync((char*)d_ws + QSUM_OFF, 0, CLASS_NUM * 128 * sizeof(float), stream);

  prep_q8<<<dim3(NGRP), dim3(256), 0, stream>>>(queue, (char*)d_ws);

  pgc_stream<<<dim3(512), dim3(256), 0, stream>>>(
      act, ema, plab, (const char*)d_ws, out);
}

// Round 9
// 58.891 us; speedup vs baseline: 1.1642x; 1.0675x over previous
//
#include <hip/hip_runtime.h>
#include <stdint.h>

#define CLASS_NUM 7
#define QROWS 1050
#define QPAD  1152              // 72 groups * 16 rows; pad rows are zero
#define NPAD  102               // pad rows each add exp2(0)=1 to denom
#define NGRP  72
#define GPW   18                // groups per wave (NGRP / 4 waves)
#define QSUM_OFF (QPAD * 128)   // 147456: 7x128 fp32 class sums (after fp8 image)
#define C2L 2.8853900817779268f // 2/ln2 : exp(2s) = exp2(s*C2L)

typedef float f32x4 __attribute__((ext_vector_type(4)));
typedef long  long2v __attribute__((ext_vector_type(2)));

// pack 4 floats -> 4 fp8 e4m3 (OCP, RNE) in one dword
__device__ __forceinline__ unsigned pk8(float a, float b, float c, float d) {
  int v = __builtin_amdgcn_cvt_pk_fp8_f32(a, b, 0, false);
  v = __builtin_amdgcn_cvt_pk_fp8_f32(c, d, v, true);
  return (unsigned)v;
}

// ---- prep: (a) queue fp32 -> fp8 fragment-major image [g][lane][k] (8B piece
// at g*2048 + lane*32 + k*8 holds queue[g*16+(lane&15)][k*32+(lane>>4)*8 ..+8]);
// (b) per-class column sums via run-based atomics (qsum zeroed by memset).
__global__ __launch_bounds__(256) void prep_q8(
    const float* __restrict__ queue, char* __restrict__ ws)
{
  const int g = blockIdx.x, tid = threadIdx.x;
  // (a) fp8 conversion
  {
    const int lane = tid >> 2, k = tid & 3;
    const int row = g * 16 + (lane & 15);
    const int col = k * 32 + (lane >> 4) * 8;
    uint2 u = {0u, 0u};
    if (row < QROWS) {
      const float4 v0 = *(const float4*)(queue + row * 128 + col);
      const float4 v1 = *(const float4*)(queue + row * 128 + col + 4);
      u.x = pk8(v0.x, v0.y, v0.z, v0.w);
      u.y = pk8(v1.x, v1.y, v1.z, v1.w);
    }
    *(uint2*)(ws + (size_t)g * 2048 + tid * 8) = u;
  }
  // (b) class sums: col = tid&127, rows g*16 + (tid>>7)*8 .. +8
  {
    float* qsum = (float*)(ws + QSUM_OFF);
    const int col = tid & 127;
    const int rbase = g * 16 + (tid >> 7) * 8;
    int c0 = -1; float s = 0.f;
#pragma unroll
    for (int rr = 0; rr < 8; ++rr) {
      const int row = rbase + rr;
      if (row < QROWS) {
        const int c = (row * 6991) >> 20;          // row/150, exact here
        if (c != c0) {
          if (c0 >= 0) atomicAdd(&qsum[c0 * 128 + col], s);
          c0 = c; s = 0.f;
        }
        s += queue[row * 128 + col];
      }
    }
    if (c0 >= 0) atomicAdd(&qsum[c0 * 128 + col], s);
  }
}

// ---- main: 2048 blocks x 256 thr (4 waves). Block owns 32 B-rows; each wave
// sweeps a QUARTER of the queue (18 groups) for those rows -> 8192 waves total
// (8 waves/SIMD). Partial denominators combine via LDS at the end.
__global__ __launch_bounds__(256, 8) void pgc_stream(
    const float* __restrict__ act, const float* __restrict__ ema,
    const float* __restrict__ plab, const char* __restrict__ ws,
    float* __restrict__ out)
{
  __shared__ __align__(16) char aT[4096];    // 32-row fp8 A tile, frag-major
  __shared__ float s_lpos[32], s_pd[32];
  __shared__ float dnp[4][32];

  const int tid = threadIdx.x, lane = tid & 63, wave = tid >> 6;
  const int lo = lane & 15, hi = lane >> 4;

  // ---- prologue: 8 threads/row; norms, lpos, label, pos-dot, A->fp8 frag-major
  {
    const int r = tid >> 3, j8 = tid & 7;
    const long grow = (long)blockIdx.x * 32 + r;
    const float* ap = act + grow * 128 + j8 * 16;
    const float* ep = ema + grow * 128 + j8 * 16;
    f32x4 a4[4];
    float a2 = 0.f, e2 = 0.f, ae = 0.f;
#pragma unroll
    for (int u = 0; u < 4; ++u) {
      a4[u] = *(const f32x4*)(ap + 4 * u);
      const float4 ev = *(const float4*)(ep + 4 * u);
      a2 += a4[u].x*a4[u].x + a4[u].y*a4[u].y + a4[u].z*a4[u].z + a4[u].w*a4[u].w;
      e2 += ev.x*ev.x + ev.y*ev.y + ev.z*ev.z + ev.w*ev.w;
      ae += a4[u].x*ev.x + a4[u].y*ev.y + a4[u].z*ev.z + a4[u].w*ev.w;
    }
#pragma unroll
    for (int m = 1; m < 8; m <<= 1) {
      a2 += __shfl_xor(a2, m);
      e2 += __shfl_xor(e2, m);
      ae += __shfl_xor(ae, m);
    }
    const float rna = rsqrtf(a2), rne = rsqrtf(e2);

    // argmax over 7 classes via 8-lane vote (first-max tie rule)
    float v = (j8 < CLASS_NUM) ? plab[grow * CLASS_NUM + j8] : -3.4e38f;
    int bi = j8;
#pragma unroll
    for (int m = 1; m < 8; m <<= 1) {
      const float ov = __shfl_xor(v, m);
      const int   oi = __shfl_xor(bi, m);
      if (ov > v || (ov == v && oi < bi)) { v = ov; bi = oi; }
    }

    // positive-sum via precomputed class sums (fp32-exact)
    const float* qs = (const float*)(ws + QSUM_OFF) + bi * 128 + j8 * 16;
    float pdot = 0.f;
#pragma unroll
    for (int u = 0; u < 4; ++u) {
      const float4 qv = *(const float4*)(qs + 4 * u);
      pdot += a4[u].x*qv.x + a4[u].y*qv.y + a4[u].z*qv.z + a4[u].w*qv.w;
    }
#pragma unroll
    for (int m = 1; m < 8; m <<= 1) pdot += __shfl_xor(pdot, m);

    if (j8 == 0) {
      s_lpos[r] = ae * rna * rne * C2L;
      s_pd[r]   = pdot * rna;
    }

    // stage A frag-major: addr = s*2048 + (hi_*16 + lr)*32 + k*8
    const float sc = rna * C2L;     // pre-scale so MFMA output is 2s/ln2
    const int s = r >> 4, lr = r & 15, k = j8 >> 1;
#pragma unroll
    for (int h2 = 0; h2 < 2; ++h2) {
      const int hi_ = (j8 & 1) * 2 + h2;
      const f32x4 x = a4[h2 * 2], y = a4[h2 * 2 + 1];
      uint2 u;
      u.x = pk8(x.x * sc, x.y * sc, x.z * sc, x.w * sc);
      u.y = pk8(y.x * sc, y.y * sc, y.z * sc, y.w * sc);
      *(uint2*)(aT + s * 2048 + (hi_ * 16 + lr) * 32 + k * 8) = u;
    }
  }
  __syncthreads();

  // A fragments (all 4 waves read the same 32 rows; LDS broadcast)
  const long2v la0 = *(const long2v*)(aT + lane * 32);
  const long2v la1 = *(const long2v*)(aT + lane * 32 + 16);
  const long2v lb0 = *(const long2v*)(aT + 2048 + lane * 32);
  const long2v lb1 = *(const long2v*)(aT + 2048 + lane * 32 + 16);

  float dn0[4] = {0.f, 0.f, 0.f, 0.f};
  float dn1[4] = {0.f, 0.f, 0.f, 0.f};
  const f32x4 Z = {0.f, 0.f, 0.f, 0.f};
  const char* qp = ws + (size_t)(wave * GPW) * 2048 + (size_t)lane * 32;

  long2v B0a, B0b, B1a, B1b;
#define LOADG(Xa, Xb, G)                                                \
  { Xa = *(const long2v*)(qp + (G) * 2048);                             \
    Xb = *(const long2v*)(qp + (G) * 2048 + 16); }
#define COMPG(Xa, Xb)                                                   \
  { f32x4 c0 = Z, c1 = Z;                                               \
    c0 = __builtin_amdgcn_mfma_f32_16x16x32_fp8_fp8(la0[0], Xa[0], c0, 0, 0, 0); \
    c1 = __builtin_amdgcn_mfma_f32_16x16x32_fp8_fp8(lb0[0], Xa[0], c1, 0, 0, 0); \
    c0 = __builtin_amdgcn_mfma_f32_16x16x32_fp8_fp8(la0[1], Xa[1], c0, 0, 0, 0); \
    c1 = __builtin_amdgcn_mfma_f32_16x16x32_fp8_fp8(lb0[1], Xa[1], c1, 0, 0, 0); \
    c0 = __builtin_amdgcn_mfma_f32_16x16x32_fp8_fp8(la1[0], Xb[0], c0, 0, 0, 0); \
    c1 = __builtin_amdgcn_mfma_f32_16x16x32_fp8_fp8(lb1[0], Xb[0], c1, 0, 0, 0); \
    c0 = __builtin_amdgcn_mfma_f32_16x16x32_fp8_fp8(la1[1], Xb[1], c0, 0, 0, 0); \
    c1 = __builtin_amdgcn_mfma_f32_16x16x32_fp8_fp8(lb1[1], Xb[1], c1, 0, 0, 0); \
    _Pragma("unroll")                                                   \
    for (int rg = 0; rg < 4; ++rg) {                                    \
      dn0[rg] += exp2f(c0[rg]);                                         \
      dn1[rg] += exp2f(c1[rg]);                                         \
    } }

  LOADG(B0a, B0b, 0)
  LOADG(B1a, B1b, 1)
#pragma unroll 1
  for (int g = 0; g < GPW - 2; g += 2) {
    COMPG(B0a, B0b) LOADG(B0a, B0b, g + 2)
    COMPG(B1a, B1b) LOADG(B1a, B1b, g + 3)
  }
  COMPG(B0a, B0b)
  COMPG(B1a, B1b)
#undef LOADG
#undef COMPG

  // reduce across the 16 q-column lanes of each row
#pragma unroll
  for (int rg = 0; rg < 4; ++rg)
#pragma unroll
    for (int m = 1; m < 16; m <<= 1) {
      dn0[rg] += __shfl_xor(dn0[rg], m);
      dn1[rg] += __shfl_xor(dn1[rg], m);
    }

  if (lo == 0) {
#pragma unroll
    for (int rg = 0; rg < 4; ++rg) {
      dnp[wave][hi * 4 + rg]      = dn0[rg];
      dnp[wave][16 + hi * 4 + rg] = dn1[rg];
    }
  }
  __syncthreads();

  // epilogue: thread i (< 32) owns block-row i
  if (tid < 32) {
    const int i = tid;
    const float dtot = dnp[0][i] + dnp[1][i] + dnp[2][i] + dnp[3][i];
    const float lp   = exp2f(s_lpos[i]);        // exp(2*<f,ema_f>)
    const float dnf  = lp + dtot - (float)NPAD;
    float loss = -logf(lp / dnf + 1e-8f) + 150.0f * logf(dnf) - 2.0f * s_pd[i];
#pragma unroll
    for (int m = 1; m < 32; m <<= 1) loss += __shfl_xor(loss, m);
    if (tid == 0)
      atomicAdd(out, loss * (1.0f / (151.0f * 65536.0f)));
  }
}

extern "C" void kernel_launch(void* const* d_in, const int* in_sizes, int n_in,
                              void* d_out, int out_size, void* d_ws, size_t ws_size,
                              hipStream_t stream) {
  const float* act   = (const float*)d_in[0];
  const float* ema   = (const float*)d_in[1];
  const float* plab  = (const float*)d_in[2];
  const float* queue = (const float*)d_in[3];
  float* out = (float*)d_out;

  hipMemsetAsync(d_out, 0, sizeof(float), stream);
  hipMemsetAsync((char*)d_ws + QSUM_OFF, 0, CLASS_NUM * 128 * sizeof(float), stream);

  prep_q8<<<dim3(NGRP), dim3(256), 0, stream>>>(queue, (char*)d_ws);

  pgc_stream<<<dim3(65536 / 32), dim3(256), 0, stream>>>(
      act, ema, plab, (const char*)d_ws, out);
}

// Round 10
// 57.943 us; speedup vs baseline: 1.1832x; 1.0164x over previous
//
#include <hip/hip_runtime.h>
#include <stdint.h>

#define CLASS_NUM 7
#define QROWS 1050
#define QPAD  1152              // 72 groups * 16 rows; pad rows are zero
#define NPAD  102               // pad rows each add exp2(0)=1 to denom
#define NGRP  72
#define GPW   18                // groups per wave (NGRP / 4 waves)
#define QSUM_OFF (QPAD * 128)   // 147456: 7x128 fp32 class sums (after fp8 image)
#define C2L 2.8853900817779268f // 2/ln2 : exp(2s) = exp2(s*C2L)

typedef float f32x4 __attribute__((ext_vector_type(4)));
typedef long  long2v __attribute__((ext_vector_type(2)));

// raw v_exp_f32 (2^x). Inputs here are bounded (|x| <= ~6), no fixup needed.
__device__ __forceinline__ float fexp2(float x) {
  float r;
  asm("v_exp_f32 %0, %1" : "=v"(r) : "v"(x));
  return r;
}

// pack 4 floats -> 4 fp8 e4m3 (OCP, RNE) in one dword
__device__ __forceinline__ unsigned pk8(float a, float b, float c, float d) {
  int v = __builtin_amdgcn_cvt_pk_fp8_f32(a, b, 0, false);
  v = __builtin_amdgcn_cvt_pk_fp8_f32(c, d, v, true);
  return (unsigned)v;
}

// ---- prep: (a) queue fp32 -> fp8 fragment-major image [g][lane][k] (8B piece
// at g*2048 + lane*32 + k*8 holds queue[g*16+(lane&15)][k*32+(lane>>4)*8 ..+8]);
// (b) per-class column sums via run-based atomics (qsum zeroed by memset).
__global__ __launch_bounds__(256) void prep_q8(
    const float* __restrict__ queue, char* __restrict__ ws)
{
  const int g = blockIdx.x, tid = threadIdx.x;
  // (a) fp8 conversion
  {
    const int lane = tid >> 2, k = tid & 3;
    const int row = g * 16 + (lane & 15);
    const int col = k * 32 + (lane >> 4) * 8;
    uint2 u = {0u, 0u};
    if (row < QROWS) {
      const float4 v0 = *(const float4*)(queue + row * 128 + col);
      const float4 v1 = *(const float4*)(queue + row * 128 + col + 4);
      u.x = pk8(v0.x, v0.y, v0.z, v0.w);
      u.y = pk8(v1.x, v1.y, v1.z, v1.w);
    }
    *(uint2*)(ws + (size_t)g * 2048 + tid * 8) = u;
  }
  // (b) class sums: col = tid&127, rows g*16 + (tid>>7)*8 .. +8
  {
    float* qsum = (float*)(ws + QSUM_OFF);
    const int col = tid & 127;
    const int rbase = g * 16 + (tid >> 7) * 8;
    int c0 = -1; float s = 0.f;
#pragma unroll
    for (int rr = 0; rr < 8; ++rr) {
      const int row = rbase + rr;
      if (row < QROWS) {
        const int c = (row * 6991) >> 20;          // row/150, exact here
        if (c != c0) {
          if (c0 >= 0) atomicAdd(&qsum[c0 * 128 + col], s);
          c0 = c; s = 0.f;
        }
        s += queue[row * 128 + col];
      }
    }
    if (c0 >= 0) atomicAdd(&qsum[c0 * 128 + col], s);
  }
}

// ---- main: 2048 blocks x 256 thr (4 waves). Block owns 32 B-rows; each wave
// sweeps a QUARTER of the queue (18 groups) -> 8192 waves (8/SIMD potential).
// launch_bounds(256,4): 128-reg cap so the ~64-reg body does NOT spill;
// runtime occupancy is set by actual usage (~64 -> still 8 waves/SIMD).
__global__ __launch_bounds__(256, 4) void pgc_stream(
    const float* __restrict__ act, const float* __restrict__ ema,
    const float* __restrict__ plab, const char* __restrict__ ws,
    float* __restrict__ out)
{
  __shared__ __align__(16) char aT[4096];    // 32-row fp8 A tile, frag-major
  __shared__ float s_lpos[32], s_pd[32];
  __shared__ float dnp[4][32];

  const int tid = threadIdx.x, lane = tid & 63, wave = tid >> 6;
  const int lo = lane & 15, hi = lane >> 4;

  // ---- prologue: 8 threads/row; norms, lpos, label, pos-dot, A->fp8 frag-major
  {
    const int r = tid >> 3, j8 = tid & 7;
    const long grow = (long)blockIdx.x * 32 + r;
    const float* ap = act + grow * 128 + j8 * 16;
    const float* ep = ema + grow * 128 + j8 * 16;
    f32x4 a4[4];
    float a2 = 0.f, e2 = 0.f, ae = 0.f;
#pragma unroll
    for (int u = 0; u < 4; ++u) {
      a4[u] = *(const f32x4*)(ap + 4 * u);
      const float4 ev = *(const float4*)(ep + 4 * u);
      a2 += a4[u].x*a4[u].x + a4[u].y*a4[u].y + a4[u].z*a4[u].z + a4[u].w*a4[u].w;
      e2 += ev.x*ev.x + ev.y*ev.y + ev.z*ev.z + ev.w*ev.w;
      ae += a4[u].x*ev.x + a4[u].y*ev.y + a4[u].z*ev.z + a4[u].w*ev.w;
    }
#pragma unroll
    for (int m = 1; m < 8; m <<= 1) {
      a2 += __shfl_xor(a2, m);
      e2 += __shfl_xor(e2, m);
      ae += __shfl_xor(ae, m);
    }
    const float rna = rsqrtf(a2), rne = rsqrtf(e2);

    // argmax over 7 classes via 8-lane vote (first-max tie rule)
    float v = (j8 < CLASS_NUM) ? plab[grow * CLASS_NUM + j8] : -3.4e38f;
    int bi = j8;
#pragma unroll
    for (int m = 1; m < 8; m <<= 1) {
      const float ov = __shfl_xor(v, m);
      const int   oi = __shfl_xor(bi, m);
      if (ov > v || (ov == v && oi < bi)) { v = ov; bi = oi; }
    }

    // positive-sum via precomputed class sums (fp32-exact)
    const float* qs = (const float*)(ws + QSUM_OFF) + bi * 128 + j8 * 16;
    float pdot = 0.f;
#pragma unroll
    for (int u = 0; u < 4; ++u) {
      const float4 qv = *(const float4*)(qs + 4 * u);
      pdot += a4[u].x*qv.x + a4[u].y*qv.y + a4[u].z*qv.z + a4[u].w*qv.w;
    }
#pragma unroll
    for (int m = 1; m < 8; m <<= 1) pdot += __shfl_xor(pdot, m);

    if (j8 == 0) {
      s_lpos[r] = ae * rna * rne * C2L;
      s_pd[r]   = pdot * rna;
    }

    // stage A frag-major: addr = s*2048 + (hi_*16 + lr)*32 + k*8
    const float sc = rna * C2L;     // pre-scale so MFMA output is 2s/ln2
    const int s = r >> 4, lr = r & 15, k = j8 >> 1;
#pragma unroll
    for (int h2 = 0; h2 < 2; ++h2) {
      const int hi_ = (j8 & 1) * 2 + h2;
      const f32x4 x = a4[h2 * 2], y = a4[h2 * 2 + 1];
      uint2 u;
      u.x = pk8(x.x * sc, x.y * sc, x.z * sc, x.w * sc);
      u.y = pk8(y.x * sc, y.y * sc, y.z * sc, y.w * sc);
      *(uint2*)(aT + s * 2048 + (hi_ * 16 + lr) * 32 + k * 8) = u;
    }
  }
  __syncthreads();

  // A fragments (all 4 waves read the same 32 rows; LDS broadcast)
  const long2v la0 = *(const long2v*)(aT + lane * 32);
  const long2v la1 = *(const long2v*)(aT + lane * 32 + 16);
  const long2v lb0 = *(const long2v*)(aT + 2048 + lane * 32);
  const long2v lb1 = *(const long2v*)(aT + 2048 + lane * 32 + 16);

  float dn0[4] = {0.f, 0.f, 0.f, 0.f};
  float dn1[4] = {0.f, 0.f, 0.f, 0.f};
  const f32x4 Z = {0.f, 0.f, 0.f, 0.f};
  const char* qp = ws + (size_t)(wave * GPW) * 2048 + (size_t)lane * 32;

  long2v B0a, B0b, B1a, B1b;
#define LOADG(Xa, Xb, G)                                                \
  { Xa = *(const long2v*)(qp + (G) * 2048);                             \
    Xb = *(const long2v*)(qp + (G) * 2048 + 16); }
#define COMPG(Xa, Xb)                                                   \
  { f32x4 c0 = Z, c1 = Z;                                               \
    c0 = __builtin_amdgcn_mfma_f32_16x16x32_fp8_fp8(la0[0], Xa[0], c0, 0, 0, 0); \
    c1 = __builtin_amdgcn_mfma_f32_16x16x32_fp8_fp8(lb0[0], Xa[0], c1, 0, 0, 0); \
    c0 = __builtin_amdgcn_mfma_f32_16x16x32_fp8_fp8(la0[1], Xa[1], c0, 0, 0, 0); \
    c1 = __builtin_amdgcn_mfma_f32_16x16x32_fp8_fp8(lb0[1], Xa[1], c1, 0, 0, 0); \
    c0 = __builtin_amdgcn_mfma_f32_16x16x32_fp8_fp8(la1[0], Xb[0], c0, 0, 0, 0); \
    c1 = __builtin_amdgcn_mfma_f32_16x16x32_fp8_fp8(lb1[0], Xb[0], c1, 0, 0, 0); \
    c0 = __builtin_amdgcn_mfma_f32_16x16x32_fp8_fp8(la1[1], Xb[1], c0, 0, 0, 0); \
    c1 = __builtin_amdgcn_mfma_f32_16x16x32_fp8_fp8(lb1[1], Xb[1], c1, 0, 0, 0); \
    _Pragma("unroll")                                                   \
    for (int rg = 0; rg < 4; ++rg) {                                    \
      dn0[rg] += fexp2(c0[rg]);                                         \
      dn1[rg] += fexp2(c1[rg]);                                         \
    } }

  LOADG(B0a, B0b, 0)
  LOADG(B1a, B1b, 1)
#pragma unroll 1
  for (int g = 0; g < GPW - 2; g += 2) {
    COMPG(B0a, B0b) LOADG(B0a, B0b, g + 2)
    COMPG(B1a, B1b) LOADG(B1a, B1b, g + 3)
  }
  COMPG(B0a, B0b)
  COMPG(B1a, B1b)
#undef LOADG
#undef COMPG

  // reduce across the 16 q-column lanes of each row
#pragma unroll
  for (int rg = 0; rg < 4; ++rg)
#pragma unroll
    for (int m = 1; m < 16; m <<= 1) {
      dn0[rg] += __shfl_xor(dn0[rg], m);
      dn1[rg] += __shfl_xor(dn1[rg], m);
    }

  if (lo == 0) {
#pragma unroll
    for (int rg = 0; rg < 4; ++rg) {
      dnp[wave][hi * 4 + rg]      = dn0[rg];
      dnp[wave][16 + hi * 4 + rg] = dn1[rg];
    }
  }
  __syncthreads();

  // epilogue: thread i (< 32) owns block-row i
  if (tid < 32) {
    const int i = tid;
    const float dtot = dnp[0][i] + dnp[1][i] + dnp[2][i] + dnp[3][i];
    const float lp   = fexp2(s_lpos[i]);        // exp(2*<f,ema_f>)
    const float dnf  = lp + dtot - (float)NPAD;
    float loss = -logf(lp / dnf + 1e-8f) + 150.0f * logf(dnf) - 2.0f * s_pd[i];
#pragma unroll
    for (int m = 1; m < 32; m <<= 1) loss += __shfl_xor(loss, m);
    if (tid == 0)
      atomicAdd(out, loss * (1.0f / (151.0f * 65536.0f)));
  }
}

extern "C" void kernel_launch(void* const* d_in, const int* in_sizes, int n_in,
                              void* d_out, int out_size, void* d_ws, size_t ws_size,
                              hipStream_t stream) {
  const float* act   = (const float*)d_in[0];
  const float* ema   = (const float*)d_in[1];
  const float* plab  = (const float*)d_in[2];
  const float* queue = (const float*)d_in[3];
  float* out = (float*)d_out;

  hipMemsetAsync(d_out, 0, sizeof(float), stream);
  hipMemsetAsync((char*)d_ws + QSUM_OFF, 0, CLASS_NUM * 128 * sizeof(float), stream);

  prep_q8<<<dim3(NGRP), dim3(256), 0, stream>>>(queue, (char*)d_ws);

  pgc_stream<<<dim3(65536 / 32), dim3(256), 0, stream>>>(
      act, ema, plab, (const char*)d_ws, out);
}

// Round 11
// 54.350 us; speedup vs baseline: 1.2614x; 1.0661x over previous
//
#include <hip/hip_runtime.h>
#include <stdint.h>

#define CLASS_NUM 7
#define QROWS 1050
#define QPAD  1152              // 72 groups * 16 rows; pad rows are zero
#define NPAD  102               // pad rows each add exp2(0)=1 to denom
#define NGRP  72
#define GPW   18                // groups per wave (NGRP / 4 waves)
#define QSUM_OFF (QPAD * 128)   // 147456: 7x128 fp32 class sums (after fp8 image)
#define C2L 2.8853900817779268f // 2/ln2 : exp(2s) = exp2(s*C2L)

typedef float f32x4 __attribute__((ext_vector_type(4)));
typedef long  long2v __attribute__((ext_vector_type(2)));

// pack 4 floats -> 4 fp8 e4m3 (OCP, RNE) in one dword
__device__ __forceinline__ unsigned pk8(float a, float b, float c, float d) {
  int v = __builtin_amdgcn_cvt_pk_fp8_f32(a, b, 0, false);
  v = __builtin_amdgcn_cvt_pk_fp8_f32(c, d, v, true);
  return (unsigned)v;
}

// ---- prep: (a) queue fp32 -> fp8 fragment-major image [g][lane][k] (8B piece
// at g*2048 + lane*32 + k*8 holds queue[g*16+(lane&15)][k*32+(lane>>4)*8 ..+8]);
// (b) per-class column sums via run-based atomics (qsum zeroed by memset).
__global__ __launch_bounds__(256) void prep_q8(
    const float* __restrict__ queue, char* __restrict__ ws)
{
  const int g = blockIdx.x, tid = threadIdx.x;
  // (a) fp8 conversion
  {
    const int lane = tid >> 2, k = tid & 3;
    const int row = g * 16 + (lane & 15);
    const int col = k * 32 + (lane >> 4) * 8;
    uint2 u = {0u, 0u};
    if (row < QROWS) {
      const float4 v0 = *(const float4*)(queue + row * 128 + col);
      const float4 v1 = *(const float4*)(queue + row * 128 + col + 4);
      u.x = pk8(v0.x, v0.y, v0.z, v0.w);
      u.y = pk8(v1.x, v1.y, v1.z, v1.w);
    }
    *(uint2*)(ws + (size_t)g * 2048 + tid * 8) = u;
  }
  // (b) class sums: col = tid&127, rows g*16 + (tid>>7)*8 .. +8
  {
    float* qsum = (float*)(ws + QSUM_OFF);
    const int col = tid & 127;
    const int rbase = g * 16 + (tid >> 7) * 8;
    int c0 = -1; float s = 0.f;
#pragma unroll
    for (int rr = 0; rr < 8; ++rr) {
      const int row = rbase + rr;
      if (row < QROWS) {
        const int c = (row * 6991) >> 20;          // row/150, exact here
        if (c != c0) {
          if (c0 >= 0) atomicAdd(&qsum[c0 * 128 + col], s);
          c0 = c; s = 0.f;
        }
        s += queue[row * 128 + col];
      }
    }
    if (c0 >= 0) atomicAdd(&qsum[c0 * 128 + col], s);
  }
}

// ---- main: 2048 blocks x 256 thr (4 waves). Block owns 32 B-rows; each wave
// sweeps a QUARTER of the queue (18 groups) -> 8192 waves. launch_bounds(256,2)
// relaxes the allocator (R10's (256,4) squeezed to 36 VGPR and serialized all
// loads); natural ~64 regs still allows 8 waves/SIMD at runtime.
__global__ __launch_bounds__(256, 2) void pgc_stream(
    const float* __restrict__ act, const float* __restrict__ ema,
    const float* __restrict__ plab, const char* __restrict__ ws,
    float* __restrict__ out)
{
  __shared__ __align__(16) char aT[4096];    // 32-row fp8 A tile, frag-major
  __shared__ float s_lpos[32], s_pd[32];
  __shared__ float dnp[4][32];

  const int tid = threadIdx.x, lane = tid & 63, wave = tid >> 6;
  const int lo = lane & 15, hi = lane >> 4;

  // ---- prologue: 8 threads/row. Issue ALL independent loads first (9-deep MLP)
  {
    const int r = tid >> 3, j8 = tid & 7;
    const long grow = (long)blockIdx.x * 32 + r;
    const float* ap = act + grow * 128 + j8 * 16;
    const float* ep = ema + grow * 128 + j8 * 16;

    float pv = (j8 < CLASS_NUM) ? plab[grow * CLASS_NUM + j8] : -3.4e38f;
    f32x4 a4[4], e4[4];
#pragma unroll
    for (int u = 0; u < 4; ++u) a4[u] = *(const f32x4*)(ap + 4 * u);
#pragma unroll
    for (int u = 0; u < 4; ++u) e4[u] = *(const f32x4*)(ep + 4 * u);

    float a2 = 0.f, e2 = 0.f, ae = 0.f;
#pragma unroll
    for (int u = 0; u < 4; ++u) {
      a2 += a4[u].x*a4[u].x + a4[u].y*a4[u].y + a4[u].z*a4[u].z + a4[u].w*a4[u].w;
      e2 += e4[u].x*e4[u].x + e4[u].y*e4[u].y + e4[u].z*e4[u].z + e4[u].w*e4[u].w;
      ae += a4[u].x*e4[u].x + a4[u].y*e4[u].y + a4[u].z*e4[u].z + a4[u].w*e4[u].w;
    }
#pragma unroll
    for (int m = 1; m < 8; m <<= 1) {
      a2 += __shfl_xor(a2, m);
      e2 += __shfl_xor(e2, m);
      ae += __shfl_xor(ae, m);
    }
    const float rna = rsqrtf(a2), rne = rsqrtf(e2);

    // argmax over 7 classes via 8-lane vote (first-max tie rule)
    int bi = j8;
#pragma unroll
    for (int m = 1; m < 8; m <<= 1) {
      const float ov = __shfl_xor(pv, m);
      const int   oi = __shfl_xor(bi, m);
      if (ov > pv || (ov == pv && oi < bi)) { pv = ov; bi = oi; }
    }

    // positive-sum via precomputed class sums (fp32-exact)
    const float* qs = (const float*)(ws + QSUM_OFF) + bi * 128 + j8 * 16;
    float pdot = 0.f;
#pragma unroll
    for (int u = 0; u < 4; ++u) {
      const float4 qv = *(const float4*)(qs + 4 * u);
      pdot += a4[u].x*qv.x + a4[u].y*qv.y + a4[u].z*qv.z + a4[u].w*qv.w;
    }
#pragma unroll
    for (int m = 1; m < 8; m <<= 1) pdot += __shfl_xor(pdot, m);

    if (j8 == 0) {
      s_lpos[r] = ae * rna * rne * C2L;
      s_pd[r]   = pdot * rna;
    }

    // stage A frag-major: addr = s*2048 + (hi_*16 + lr)*32 + k*8
    const float sc = rna * C2L;     // pre-scale so MFMA output is 2s/ln2
    const int s = r >> 4, lr = r & 15, k = j8 >> 1;
#pragma unroll
    for (int h2 = 0; h2 < 2; ++h2) {
      const int hi_ = (j8 & 1) * 2 + h2;
      const f32x4 x = a4[h2 * 2], y = a4[h2 * 2 + 1];
      uint2 u;
      u.x = pk8(x.x * sc, x.y * sc, x.z * sc, x.w * sc);
      u.y = pk8(y.x * sc, y.y * sc, y.z * sc, y.w * sc);
      *(uint2*)(aT + s * 2048 + (hi_ * 16 + lr) * 32 + k * 8) = u;
    }
  }
  __syncthreads();

  // A fragments (all 4 waves read the same 32 rows; LDS broadcast)
  const long2v la0 = *(const long2v*)(aT + lane * 32);
  const long2v la1 = *(const long2v*)(aT + lane * 32 + 16);
  const long2v lb0 = *(const long2v*)(aT + 2048 + lane * 32);
  const long2v lb1 = *(const long2v*)(aT + 2048 + lane * 32 + 16);

  float dn0[4] = {0.f, 0.f, 0.f, 0.f};
  float dn1[4] = {0.f, 0.f, 0.f, 0.f};
  const f32x4 Z = {0.f, 0.f, 0.f, 0.f};
  const char* qp = ws + (size_t)(wave * GPW) * 2048 + (size_t)lane * 32;

  long2v B0a, B0b, B1a, B1b;
#define LOADG(Xa, Xb, G)                                                \
  { Xa = *(const long2v*)(qp + (G) * 2048);                             \
    Xb = *(const long2v*)(qp + (G) * 2048 + 16); }
#define COMPG(Xa, Xb)                                                   \
  { f32x4 c0 = Z, c1 = Z;                                               \
    c0 = __builtin_amdgcn_mfma_f32_16x16x32_fp8_fp8(la0[0], Xa[0], c0, 0, 0, 0); \
    c1 = __builtin_amdgcn_mfma_f32_16x16x32_fp8_fp8(lb0[0], Xa[0], c1, 0, 0, 0); \
    c0 = __builtin_amdgcn_mfma_f32_16x16x32_fp8_fp8(la0[1], Xa[1], c0, 0, 0, 0); \
    c1 = __builtin_amdgcn_mfma_f32_16x16x32_fp8_fp8(lb0[1], Xa[1], c1, 0, 0, 0); \
    c0 = __builtin_amdgcn_mfma_f32_16x16x32_fp8_fp8(la1[0], Xb[0], c0, 0, 0, 0); \
    c1 = __builtin_amdgcn_mfma_f32_16x16x32_fp8_fp8(lb1[0], Xb[0], c1, 0, 0, 0); \
    c0 = __builtin_amdgcn_mfma_f32_16x16x32_fp8_fp8(la1[1], Xb[1], c0, 0, 0, 0); \
    c1 = __builtin_amdgcn_mfma_f32_16x16x32_fp8_fp8(lb1[1], Xb[1], c1, 0, 0, 0); \
    _Pragma("unroll")                                                   \
    for (int rg = 0; rg < 4; ++rg) {                                    \
      dn0[rg] += exp2f(c0[rg]);                                         \
      dn1[rg] += exp2f(c1[rg]);                                         \
    } }

  LOADG(B0a, B0b, 0)
  LOADG(B1a, B1b, 1)
#pragma unroll 1
  for (int g = 0; g < GPW - 2; g += 2) {
    COMPG(B0a, B0b) LOADG(B0a, B0b, g + 2)
    COMPG(B1a, B1b) LOADG(B1a, B1b, g + 3)
  }
  COMPG(B0a, B0b)
  COMPG(B1a, B1b)
#undef LOADG
#undef COMPG

  // reduce across the 16 q-column lanes of each row
#pragma unroll
  for (int rg = 0; rg < 4; ++rg)
#pragma unroll
    for (int m = 1; m < 16; m <<= 1) {
      dn0[rg] += __shfl_xor(dn0[rg], m);
      dn1[rg] += __shfl_xor(dn1[rg], m);
    }

  if (lo == 0) {
#pragma unroll
    for (int rg = 0; rg < 4; ++rg) {
      dnp[wave][hi * 4 + rg]      = dn0[rg];
      dnp[wave][16 + hi * 4 + rg] = dn1[rg];
    }
  }
  __syncthreads();

  // epilogue: thread i (< 32) owns block-row i
  if (tid < 32) {
    const int i = tid;
    const float dtot = dnp[0][i] + dnp[1][i] + dnp[2][i] + dnp[3][i];
    const float lp   = exp2f(s_lpos[i]);        // exp(2*<f,ema_f>)
    const float dnf  = lp + dtot - (float)NPAD;
    float loss = -logf(lp / dnf + 1e-8f) + 150.0f * logf(dnf) - 2.0f * s_pd[i];
#pragma unroll
    for (int m = 1; m < 32; m <<= 1) loss += __shfl_xor(loss, m);
    if (tid == 0)
      atomicAdd(out, loss * (1.0f / (151.0f * 65536.0f)));
  }
}

extern "C" void kernel_launch(void* const* d_in, const int* in_sizes, int n_in,
                              void* d_out, int out_size, void* d_ws, size_t ws_size,
                              hipStream_t stream) {
  const float* act   = (const float*)d_in[0];
  const float* ema   = (const float*)d_in[1];
  const float* plab  = (const float*)d_in[2];
  const float* queue = (const float*)d_in[3];
  float* out = (float*)d_out;

  hipMemsetAsync(d_out, 0, sizeof(float), stream);
  hipMemsetAsync((char*)d_ws + QSUM_OFF, 0, CLASS_NUM * 128 * sizeof(float), stream);

  prep_q8<<<dim3(NGRP), dim3(256), 0, stream>>>(queue, (char*)d_ws);

  pgc_stream<<<dim3(65536 / 32), dim3(256), 0, stream>>>(
      act, ema, plab, (const char*)d_ws, out);
}